// Round 7
// baseline (314.473 us; speedup 1.0000x reference)
//
#include <hip/hip_runtime.h>
#include <hip/hip_bf16.h>

// Problem: B=2048, D=512, all fp32.
// q = query@Wq.T+bq ; k,v likewise. attn[b,i,j]=q_i*k_j (rank-1!),
// softmax over j, out[b,i] = sum_j softmax_j(q_i*k_j)*v_j.
//
// Round 7: ONE fused kernel. 256 blocks x 1024 thr; block owns 8 batch rows.
// Phase A: split-bf16 MFMA projection (frags straight from global; W is
// L2-resident per XCD), qkv -> d_ws (block-local round trip through L2).
// Phase B: attention, 8-way j-sliced (4 i x 64 j per thread), kv broadcast
// reads, partial num/den reduced through LDS.

#define B_SZ 2048
#define D_SZ 512

typedef __attribute__((ext_vector_type(2))) float  f32x2;
typedef __attribute__((ext_vector_type(4))) float  f32x4;
typedef __attribute__((ext_vector_type(8))) short  bf16x8;
typedef __attribute__((ext_vector_type(8))) unsigned short u16x8;

__device__ __forceinline__ float exp2_raw(float x) {
#if defined(__has_builtin) && __has_builtin(__builtin_amdgcn_exp2f)
    return __builtin_amdgcn_exp2f(x);
#else
    return exp2f(x);
#endif
}

// Truncation split: hi = top 16 bits of fp32; lo = bf16(trunc) of residual.
// |x - hi - lo| <= 2^-14 |x|
__device__ __forceinline__ void split1(float x, unsigned short& hi, unsigned short& lo) {
    unsigned int u = __float_as_uint(x);
    hi = (unsigned short)(u >> 16);
    float r = x - __uint_as_float(u & 0xFFFF0000u);
    lo = (unsigned short)(__float_as_uint(r) >> 16);
}

__device__ __forceinline__ void split8(const float4& a, const float4& b,
                                       u16x8& h, u16x8& l) {
    unsigned short hh, ll;
    split1(a.x, hh, ll); h[0] = hh; l[0] = ll;
    split1(a.y, hh, ll); h[1] = hh; l[1] = ll;
    split1(a.z, hh, ll); h[2] = hh; l[2] = ll;
    split1(a.w, hh, ll); h[3] = hh; l[3] = ll;
    split1(b.x, hh, ll); h[4] = hh; l[4] = ll;
    split1(b.y, hh, ll); h[5] = hh; l[5] = ll;
    split1(b.z, hh, ll); h[6] = hh; l[6] = ll;
    split1(b.w, hh, ll); h[7] = hh; l[7] = ll;
}

__device__ __forceinline__ bf16x8 as_bf16x8(const u16x8& u) {
    return __builtin_bit_cast(bf16x8, u);
}

__global__ __launch_bounds__(1024) void fused_attn(
    const float* __restrict__ Xq, const float* __restrict__ Xk, const float* __restrict__ Xv,
    const float* __restrict__ Wq, const float* __restrict__ bq,
    const float* __restrict__ Wk, const float* __restrict__ bk,
    const float* __restrict__ Wv, const float* __restrict__ bv,
    float* __restrict__ qkv, float* __restrict__ out)
{
    const int blk  = blockIdx.x;          // 0..255, owns batch rows 8*blk..+8
    const int t    = threadIdx.x;         // 0..1023
    const int lane = t & 63;
    const int wv   = t >> 6;              // wave 0..15
    const int l15  = lane & 15;
    const int quad = lane >> 4;

    // ---------------- Phase A: q,k,v projections --------------------------
    // 96 jobs = 3 matrices x 32 n-tiles(16 wide); 6 jobs per wave.
    // Per job: M=16 (rows 8..15 duplicate row data, results discarded),
    // K-loop 16 tiles of 32, frags loaded straight from global fp32 + split.
    {
        const int mrow = l15 & 7;         // clamp: rows 8..15 re-read 0..7
#pragma unroll 1
        for (int jj = 0; jj < 6; ++jj) {
            const int job = jj * 16 + wv;           // 0..95
            const int mat = job >> 5;               // 0..2
            const int nt  = job & 31;               // 0..31
            const float* __restrict__ X    = (mat == 0) ? Xq : (mat == 1) ? Xk : Xv;
            const float* __restrict__ W    = (mat == 0) ? Wq : (mat == 1) ? Wk : Wv;
            const float* __restrict__ bias = (mat == 0) ? bq : (mat == 1) ? bk : bv;
            float* __restrict__ Y = qkv + (size_t)mat * B_SZ * D_SZ;

            const float* xrow = X + (size_t)(blk * 8 + mrow) * D_SZ + quad * 8;
            const float* wrow = W + (size_t)(nt * 16 + l15) * D_SZ + quad * 8;

            f32x4 acc = {0.f, 0.f, 0.f, 0.f};

            float4 xa = *(const float4*)(xrow);
            float4 xb = *(const float4*)(xrow + 4);
            float4 wa = *(const float4*)(wrow);
            float4 wb = *(const float4*)(wrow + 4);

#pragma unroll 1
            for (int kt = 0; kt < 16; ++kt) {
                u16x8 xh, xl, wh, wl;
                split8(xa, xb, xh, xl);
                split8(wa, wb, wh, wl);
                if (kt + 1 < 16) {                  // prefetch next k-tile
                    const int ko = (kt + 1) * 32;
                    xa = *(const float4*)(xrow + ko);
                    xb = *(const float4*)(xrow + ko + 4);
                    wa = *(const float4*)(wrow + ko);
                    wb = *(const float4*)(wrow + ko + 4);
                }
                acc = __builtin_amdgcn_mfma_f32_16x16x32_bf16(as_bf16x8(xh), as_bf16x8(wh), acc, 0, 0, 0);
                acc = __builtin_amdgcn_mfma_f32_16x16x32_bf16(as_bf16x8(xl), as_bf16x8(wh), acc, 0, 0, 0);
                acc = __builtin_amdgcn_mfma_f32_16x16x32_bf16(as_bf16x8(xh), as_bf16x8(wl), acc, 0, 0, 0);
            }

            // C/D: col=lane&15, row=quad*4+r; keep rows 0..7 (quads 0,1)
            if (quad < 2) {
                const int col = nt * 16 + l15;
                const float bb = bias[col];
#pragma unroll
                for (int r = 0; r < 4; ++r) {
                    const int row = quad * 4 + r;   // 0..7
                    Y[(size_t)(blk * 8 + row) * D_SZ + col] = acc[r] + bb;
                }
            }
        }
    }

    __syncthreads();   // phase-A writes drained (vmcnt(0) before s_barrier)

    // ---------------- Phase B: attention for rows 8*blk..+8 ---------------
    __shared__ float  kv[D_SZ * 2];        // interleaved kL,v
    __shared__ float2 part[8][D_SZ];       // [j-slice][i] partial {num,den}
    __shared__ float  redmax[16], redmin[16];

    const float L = 1.44269504088896340736f;  // log2(e)
    const int i0 = t & 127;
    const int js = t >> 7;                 // 0..7 (wave-uniform)
    const int jbase = js * 64;

#pragma unroll 1
    for (int bi = 0; bi < 8; ++bi) {
        const int b = blk * 8 + bi;
        const float* __restrict__ qrow = qkv + (size_t)b * D_SZ;
        const float* __restrict__ krow = qkv + (size_t)B_SZ * D_SZ + (size_t)b * D_SZ;
        const float* __restrict__ vrow = qkv + (size_t)2 * B_SZ * D_SZ + (size_t)b * D_SZ;

        float kmx = -3.0e38f, kmn = 3.0e38f;
        if (t < D_SZ) {
            float kj = krow[t] * L;
            float vj = vrow[t];
            ((float2*)kv)[t] = make_float2(kj, vj);
            kmx = kj; kmn = kj;
        }
#pragma unroll
        for (int off = 32; off > 0; off >>= 1) {
            kmx = fmaxf(kmx, __shfl_xor(kmx, off));
            kmn = fminf(kmn, __shfl_xor(kmn, off));
        }
        if (lane == 0) { redmax[wv] = kmx; redmin[wv] = kmn; }
        __syncthreads();   // kv staged, red published; orders prev part reads
#pragma unroll
        for (int w2 = 0; w2 < 16; ++w2) {
            kmx = fmaxf(kmx, redmax[w2]);
            kmn = fminf(kmn, redmin[w2]);
        }

        float qv[4], cc[4];
#pragma unroll
        for (int ii = 0; ii < 4; ++ii) {
            qv[ii] = qrow[i0 + 128 * ii];
            cc[ii] = (qv[ii] >= 0.f) ? -(qv[ii] * kmx) : -(qv[ii] * kmn);
        }

        f32x2 dnum[4] = {{0.f,0.f},{0.f,0.f},{0.f,0.f},{0.f,0.f}};
        f32x2 dden[4] = {{0.f,0.f},{0.f,0.f},{0.f,0.f},{0.f,0.f}};
#pragma unroll 4
        for (int jc = 0; jc < 64; jc += 2) {
            f32x4 p = *(const f32x4*)&kv[2 * (jbase + jc)];  // kL,v,kL,v
            f32x2 vvp = {p.y, p.w};
#pragma unroll
            for (int ii = 0; ii < 4; ++ii) {
                f32x2 e = {exp2_raw(fmaf(qv[ii], p.x, cc[ii])),
                           exp2_raw(fmaf(qv[ii], p.z, cc[ii]))};
                dden[ii] += e;
                dnum[ii] += e * vvp;
            }
        }
#pragma unroll
        for (int ii = 0; ii < 4; ++ii)
            part[js][i0 + 128 * ii] = make_float2(dnum[ii].x + dnum[ii].y,
                                                  dden[ii].x + dden[ii].y);
        __syncthreads();   // partials visible

        if (t < D_SZ) {
            float n = 0.f, d = 0.f;
#pragma unroll
            for (int s = 0; s < 8; ++s) {
                float2 pp = part[s][t];
                n += pp.x; d += pp.y;
            }
            out[(size_t)b * D_SZ + t] = n / d;
        }
    }
}

extern "C" void kernel_launch(void* const* d_in, const int* in_sizes, int n_in,
                              void* d_out, int out_size, void* d_ws, size_t ws_size,
                              hipStream_t stream) {
    const float* query = (const float*)d_in[0];
    const float* key_  = (const float*)d_in[1];
    const float* value = (const float*)d_in[2];
    const float* Wq    = (const float*)d_in[3];
    const float* bq    = (const float*)d_in[4];
    const float* Wk    = (const float*)d_in[5];
    const float* bk    = (const float*)d_in[6];
    const float* Wv    = (const float*)d_in[7];
    const float* bv    = (const float*)d_in[8];
    float* out = (float*)d_out;

    float* qkv = (float*)d_ws;  // [3][B][D] fp32 = 12.58 MB (proven available)

    fused_attn<<<B_SZ / 8, 1024, 0, stream>>>(query, key_, value,
                                              Wq, bq, Wk, bk, Wv, bv,
                                              qkv, out);
}

// Round 8
// 158.583 us; speedup vs baseline: 1.9830x; 1.9830x over previous
//
#include <hip/hip_runtime.h>
#include <hip/hip_bf16.h>

// Problem: B=2048, D=512, all fp32.
// q = query@Wq.T+bq ; k,v likewise. attn[b,i,j]=q_i*k_j (rank-1!),
// softmax over j, out[b,i] = sum_j softmax_j(q_i*k_j)*v_j.
//
// Round 8: two-kernel structure (R4 = best measured; fused R7 refuted,
// fixed harness overhead calibrated at ~52 us).
//  - gemm: R4 qkv_gemm_mfma verbatim (in-kernel split-bf16 MFMA, ~27 us).
//  - attn v2: 256 thr/block (occupancy as R4) but 4 i-rows/thread via
//    2-way j-slicing -> LDS bytes/exp halved, loop overhead amortized 2x.

#define B_SZ 2048
#define D_SZ 512

typedef __attribute__((ext_vector_type(2))) float  f32x2;
typedef __attribute__((ext_vector_type(4))) float  f32x4;
typedef __attribute__((ext_vector_type(8))) short  bf16x8;   // MFMA A/B carrier
typedef __attribute__((ext_vector_type(4))) unsigned short u16x4;

__device__ __forceinline__ float exp2_raw(float x) {
#if defined(__has_builtin) && __has_builtin(__builtin_amdgcn_exp2f)
    return __builtin_amdgcn_exp2f(x);
#else
    return exp2f(x);
#endif
}

// Truncation split: hi = top 16 bits of fp32; lo = bf16(trunc) of residual.
// |x - hi - lo| <= 2^-14 |x|
__device__ __forceinline__ void split1(float x, unsigned short& hi, unsigned short& lo) {
    unsigned int u = __float_as_uint(x);
    hi = (unsigned short)(u >> 16);
    float r = x - __uint_as_float(u & 0xFFFF0000u);
    lo = (unsigned short)(__float_as_uint(r) >> 16);
}

__device__ __forceinline__ void split4(const float4& x, u16x4& h, u16x4& l) {
    unsigned short hh, ll;
    split1(x.x, hh, ll); h.x = hh; l.x = ll;
    split1(x.y, hh, ll); h.y = hh; l.y = ll;
    split1(x.z, hh, ll); h.z = hh; l.z = ll;
    split1(x.w, hh, ll); h.w = hh; l.w = ll;
}

// ---------------------------------------------------------------------------
// GEMM (R4 verbatim, ~27 us): Y = X @ W^T + bias via split-bf16 MFMA.
// 64x64 tile, 256 thr (4 waves 2x2), BK=32, register-prefetch pipeline.
// ---------------------------------------------------------------------------
__global__ __launch_bounds__(256) void qkv_gemm_mfma(
    const float* __restrict__ Xq, const float* __restrict__ Xk, const float* __restrict__ Xv,
    const float* __restrict__ Wq, const float* __restrict__ bq,
    const float* __restrict__ Wk, const float* __restrict__ bk,
    const float* __restrict__ Wv, const float* __restrict__ bv,
    float* __restrict__ qkv_out)
{
    const int which = blockIdx.z;
    const float* __restrict__ X    = (which == 0) ? Xq : (which == 1) ? Xk : Xv;
    const float* __restrict__ W    = (which == 0) ? Wq : (which == 1) ? Wk : Wv;
    const float* __restrict__ bias = (which == 0) ? bq : (which == 1) ? bk : bv;
    float* __restrict__ Y = qkv_out + (size_t)which * B_SZ * D_SZ;

    const int t    = threadIdx.x;
    const int lane = t & 63;
    const int wv   = t >> 6;
    const int l15  = lane & 15;
    const int quad = lane >> 4;
    const int wm   = (wv >> 1) * 32;
    const int wn   = (wv & 1) * 32;
    const int m0   = blockIdx.x * 64;
    const int n0   = blockIdx.y * 64;

    __shared__ unsigned short Ahi[64][40], Alo[64][40];
    __shared__ unsigned short Bhi[64][40], Blo[64][40];

    f32x4 acc[2][2] = {{{0.f,0.f,0.f,0.f},{0.f,0.f,0.f,0.f}},
                       {{0.f,0.f,0.f,0.f},{0.f,0.f,0.f,0.f}}};

    const int r0 = t >> 3;
    const int c0 = (t & 7) * 4;
    const int r1 = r0 + 32;

    const float* Xp0 = &X[(size_t)(m0 + r0) * D_SZ + c0];
    const float* Xp1 = &X[(size_t)(m0 + r1) * D_SZ + c0];
    const float* Wp0 = &W[(size_t)(n0 + r0) * D_SZ + c0];
    const float* Wp1 = &W[(size_t)(n0 + r1) * D_SZ + c0];

    float4 xa0 = *(const float4*)(Xp0);
    float4 xa1 = *(const float4*)(Xp1);
    float4 wa0 = *(const float4*)(Wp0);
    float4 wa1 = *(const float4*)(Wp1);

    for (int kk = 0; kk < D_SZ; kk += 32) {
        __syncthreads();
        u16x4 h, l;
        split4(xa0, h, l); *(u16x4*)&Ahi[r0][c0] = h; *(u16x4*)&Alo[r0][c0] = l;
        split4(xa1, h, l); *(u16x4*)&Ahi[r1][c0] = h; *(u16x4*)&Alo[r1][c0] = l;
        split4(wa0, h, l); *(u16x4*)&Bhi[r0][c0] = h; *(u16x4*)&Blo[r0][c0] = l;
        split4(wa1, h, l); *(u16x4*)&Bhi[r1][c0] = h; *(u16x4*)&Blo[r1][c0] = l;
        __syncthreads();

        if (kk + 32 < D_SZ) {
            xa0 = *(const float4*)(Xp0 + kk + 32);
            xa1 = *(const float4*)(Xp1 + kk + 32);
            wa0 = *(const float4*)(Wp0 + kk + 32);
            wa1 = *(const float4*)(Wp1 + kk + 32);
        }

        bf16x8 ah0 = *(const bf16x8*)&Ahi[wm + l15     ][quad * 8];
        bf16x8 ah1 = *(const bf16x8*)&Ahi[wm + 16 + l15][quad * 8];
        bf16x8 al0 = *(const bf16x8*)&Alo[wm + l15     ][quad * 8];
        bf16x8 al1 = *(const bf16x8*)&Alo[wm + 16 + l15][quad * 8];
        bf16x8 bh0 = *(const bf16x8*)&Bhi[wn + l15     ][quad * 8];
        bf16x8 bh1 = *(const bf16x8*)&Bhi[wn + 16 + l15][quad * 8];
        bf16x8 bl0 = *(const bf16x8*)&Blo[wn + l15     ][quad * 8];
        bf16x8 bl1 = *(const bf16x8*)&Blo[wn + 16 + l15][quad * 8];

        acc[0][0] = __builtin_amdgcn_mfma_f32_16x16x32_bf16(ah0, bh0, acc[0][0], 0, 0, 0);
        acc[0][0] = __builtin_amdgcn_mfma_f32_16x16x32_bf16(al0, bh0, acc[0][0], 0, 0, 0);
        acc[0][0] = __builtin_amdgcn_mfma_f32_16x16x32_bf16(ah0, bl0, acc[0][0], 0, 0, 0);
        acc[0][1] = __builtin_amdgcn_mfma_f32_16x16x32_bf16(ah0, bh1, acc[0][1], 0, 0, 0);
        acc[0][1] = __builtin_amdgcn_mfma_f32_16x16x32_bf16(al0, bh1, acc[0][1], 0, 0, 0);
        acc[0][1] = __builtin_amdgcn_mfma_f32_16x16x32_bf16(ah0, bl1, acc[0][1], 0, 0, 0);
        acc[1][0] = __builtin_amdgcn_mfma_f32_16x16x32_bf16(ah1, bh0, acc[1][0], 0, 0, 0);
        acc[1][0] = __builtin_amdgcn_mfma_f32_16x16x32_bf16(al1, bh0, acc[1][0], 0, 0, 0);
        acc[1][0] = __builtin_amdgcn_mfma_f32_16x16x32_bf16(ah1, bl0, acc[1][0], 0, 0, 0);
        acc[1][1] = __builtin_amdgcn_mfma_f32_16x16x32_bf16(ah1, bh1, acc[1][1], 0, 0, 0);
        acc[1][1] = __builtin_amdgcn_mfma_f32_16x16x32_bf16(al1, bh1, acc[1][1], 0, 0, 0);
        acc[1][1] = __builtin_amdgcn_mfma_f32_16x16x32_bf16(ah1, bl1, acc[1][1], 0, 0, 0);
    }

#pragma unroll
    for (int ni = 0; ni < 2; ++ni) {
        const int col = n0 + wn + ni * 16 + l15;
        const float bb = bias[col];
#pragma unroll
        for (int mi = 0; mi < 2; ++mi) {
            const int row = m0 + wm + mi * 16 + quad * 4;
#pragma unroll
            for (int r = 0; r < 4; ++r) {
                Y[(size_t)(row + r) * D_SZ + col] = acc[mi][ni][r] + bb;
            }
        }
    }
}

// ---------------------------------------------------------------------------
// attn v2: out[b,i] = sum_j exp(q_i*k_j - m_i)*v_j / den; m_i via kmax/kmin.
// One block (256 thr) per b. 2-way j-slicing: js=t>>7 handles j-slice of 256,
// i0=t&127 handles i-rows {i0, i0+128, i0+256, i0+384}. Each ds_read_b128
// (2 j's) feeds 8 exps -> LDS bytes/exp = 2 (half of R4). Partials reduced
// through LDS. kv reads are wave-uniform broadcast (conflict-free).
// ---------------------------------------------------------------------------
__global__ __launch_bounds__(256) void attn_kernel_v2(
    const float* __restrict__ qkv, float* __restrict__ out)
{
    const int b = blockIdx.x;
    const int t = threadIdx.x;

    const float* __restrict__ q = qkv + (size_t)b * D_SZ;
    const float* __restrict__ k = qkv + (size_t)B_SZ * D_SZ + (size_t)b * D_SZ;
    const float* __restrict__ v = qkv + (size_t)2 * B_SZ * D_SZ + (size_t)b * D_SZ;

    __shared__ float  kv[D_SZ * 2];     // interleaved kL,v (4 KB)
    __shared__ float2 part[2][D_SZ];    // per-j-slice {num,den} partials (8 KB)
    __shared__ float  redmax[4], redmin[4];

    const float L = 1.44269504088896340736f;  // log2(e)

    const int i0 = t & 127;
    const int js = t >> 7;              // 0..1, wave-uniform (waves 0,1 / 2,3)
    const int jbase = js * 256;

    // 4 q rows per thread (issue early; coalesced within wave)
    float qv4[4], cc[4];
#pragma unroll
    for (int ii = 0; ii < 4; ++ii) qv4[ii] = q[i0 + 128 * ii];

    // stage kv: 2 j's per thread
    float kmaxL = -3.0e38f, kminL = 3.0e38f;
#pragma unroll
    for (int j = t; j < D_SZ; j += 256) {
        float kj = k[j] * L;
        float vj = v[j];
        *(float2*)&kv[2 * j] = make_float2(kj, vj);
        kmaxL = fmaxf(kmaxL, kj);
        kminL = fminf(kminL, kj);
    }
#pragma unroll
    for (int off = 32; off > 0; off >>= 1) {
        kmaxL = fmaxf(kmaxL, __shfl_xor(kmaxL, off));
        kminL = fminf(kminL, __shfl_xor(kminL, off));
    }
    const int wave = t >> 6;
    if ((t & 63) == 0) { redmax[wave] = kmaxL; redmin[wave] = kminL; }
    __syncthreads();   // publishes kv[] and red*
    kmaxL = fmaxf(fmaxf(redmax[0], redmax[1]), fmaxf(redmax[2], redmax[3]));
    kminL = fminf(fminf(redmin[0], redmin[1]), fminf(redmin[2], redmin[3]));

#pragma unroll
    for (int ii = 0; ii < 4; ++ii)
        cc[ii] = (qv4[ii] >= 0.f) ? -(qv4[ii] * kmaxL) : -(qv4[ii] * kminL);

    f32x2 den[4] = {{0.f,0.f},{0.f,0.f},{0.f,0.f},{0.f,0.f}};
    f32x2 num[4] = {{0.f,0.f},{0.f,0.f},{0.f,0.f},{0.f,0.f}};

#pragma unroll 4
    for (int jc = 0; jc < 256; jc += 2) {
        f32x4 p = *(const f32x4*)&kv[2 * (jbase + jc)];  // kL,v,kL,v
        f32x2 vvp = {p.y, p.w};
#pragma unroll
        for (int ii = 0; ii < 4; ++ii) {
            f32x2 e = {exp2_raw(fmaf(qv4[ii], p.x, cc[ii])),
                       exp2_raw(fmaf(qv4[ii], p.z, cc[ii]))};
            den[ii] += e;
            num[ii] += e * vvp;
        }
    }

#pragma unroll
    for (int ii = 0; ii < 4; ++ii)
        part[js][i0 + 128 * ii] = make_float2(num[ii].x + num[ii].y,
                                              den[ii].x + den[ii].y);
    __syncthreads();

    // final reduce: 2 i's per thread
#pragma unroll
    for (int i = t; i < D_SZ; i += 256) {
        float2 p0 = part[0][i];
        float2 p1 = part[1][i];
        out[(size_t)b * D_SZ + i] = (p0.x + p1.x) / (p0.y + p1.y);
    }
}

extern "C" void kernel_launch(void* const* d_in, const int* in_sizes, int n_in,
                              void* d_out, int out_size, void* d_ws, size_t ws_size,
                              hipStream_t stream) {
    const float* query = (const float*)d_in[0];
    const float* key_  = (const float*)d_in[1];
    const float* value = (const float*)d_in[2];
    const float* Wq    = (const float*)d_in[3];
    const float* bq    = (const float*)d_in[4];
    const float* Wk    = (const float*)d_in[5];
    const float* bk    = (const float*)d_in[6];
    const float* Wv    = (const float*)d_in[7];
    const float* bv    = (const float*)d_in[8];
    float* out = (float*)d_out;

    float* qkv = (float*)d_ws;  // [3][B][D] fp32 = 12.58 MB

    dim3 g1(B_SZ / 64, D_SZ / 64, 3);
    qkv_gemm_mfma<<<g1, 256, 0, stream>>>(query, key_, value, Wq, bq, Wk, bk, Wv, bv, qkv);
    attn_kernel_v2<<<B_SZ, 256, 0, stream>>>(qkv, out);
}